// Round 3
// baseline (100.678 us; speedup 1.0000x reference)
//
#include <hip/hip_runtime.h>

#define T_STEPS 128   // timesteps (4 x 32-bit mask words)
#define BR      128   // output rows per block (LDS tile = T_STEPS*BR*4 = 64 KB)

// ---------------------------------------------------------------------------
// Kernel 1: block-granularity CSR bounds for BOTH sparse inputs.
// bound[g] = lower_bound(rows, g*BR), g in [0, nb].
// ---------------------------------------------------------------------------
__global__ __launch_bounds__(256) void build_bounds_kernel(
    const int* __restrict__ lgn_rows, int nnz_l, int* __restrict__ lgn_bound,
    const int* __restrict__ bkg_rows, int nnz_b, int* __restrict__ bkg_bound,
    int nb)
{
    int g = blockIdx.x * 256 + threadIdx.x;
    if (g > nb) return;
    int target = g * BR;
    {
        int lo = 0, hi = nnz_l;
        while (lo < hi) { int mid = (lo + hi) >> 1; if (lgn_rows[mid] < target) lo = mid + 1; else hi = mid; }
        lgn_bound[g] = lo;
    }
    {
        int lo = 0, hi = nnz_b;
        while (lo < hi) { int mid = (lo + hi) >> 1; if (bkg_rows[mid] < target) lo = mid + 1; else hi = mid; }
        bkg_bound[g] = lo;
    }
}

// ---------------------------------------------------------------------------
// Kernel 2: compress both binary spike matrices (T=128, C) into uint4 per
// column (bit t of word q = spike at t = q*32 + bit).
// ---------------------------------------------------------------------------
__global__ __launch_bounds__(256) void build_masks2_kernel(
    const float* __restrict__ lgn_spikes, int lgn_C, uint4* __restrict__ lgn_mask,
    const float* __restrict__ bkg_spikes, int bkg_C, uint4* __restrict__ bkg_mask)
{
    int c = blockIdx.x * 256 + threadIdx.x;
    const float* sp;
    uint4* mask;
    int C, cc;
    if (c < lgn_C)              { sp = lgn_spikes; mask = lgn_mask; C = lgn_C; cc = c; }
    else if (c < lgn_C + bkg_C) { sp = bkg_spikes; mask = bkg_mask; C = bkg_C; cc = c - lgn_C; }
    else return;

    unsigned int m0 = 0u, m1 = 0u, m2 = 0u, m3 = 0u;
    #pragma unroll 4
    for (int t = 0; t < 32; ++t) {
        if (sp[(size_t)(t)       * C + cc] != 0.0f) m0 |= (1u << t);
        if (sp[(size_t)(t +  32) * C + cc] != 0.0f) m1 |= (1u << t);
        if (sp[(size_t)(t +  64) * C + cc] != 0.0f) m2 |= (1u << t);
        if (sp[(size_t)(t +  96) * C + cc] != 0.0f) m3 |= (1u << t);
    }
    mask[cc] = make_uint4(m0, m1, m2, m3);
}

// ---------------------------------------------------------------------------
// Kernel 3 (main): block = 128 output rows x all 128 timesteps in a 64 KB
// LDS tile acc[t][row] (bank = row&31: gather-friendly). Lanes sweep the
// block's synapse range FLAT (balanced); per synapse, iterate only the SET
// bits of the 128-bit spike mask (ctz loop) and ds_add_f32 into the tile.
// Epilogue: one coalesced write pass (out written exactly once).
// ---------------------------------------------------------------------------
__global__ __launch_bounds__(256) void sparse_scatter_kernel(
    const int* __restrict__ lgn_rows, const int* __restrict__ lgn_cols,
    const float* __restrict__ lgn_w,  const int* __restrict__ lgn_bound,
    const int* __restrict__ bkg_rows, const int* __restrict__ bkg_cols,
    const float* __restrict__ bkg_w,  const int* __restrict__ bkg_bound,
    const uint4* __restrict__ lgn_mask, const uint4* __restrict__ bkg_mask,
    int R, float* __restrict__ out)
{
    __shared__ float acc[T_STEPS * BR];
    const int tid = threadIdx.x;
    const int b   = blockIdx.x;
    const int r0  = b * BR;

    // zero the tile
    float4* az = (float4*)acc;
    #pragma unroll
    for (int k = 0; k < (T_STEPS * BR / 4) / 256; ++k)
        az[k * 256 + tid] = make_float4(0.f, 0.f, 0.f, 0.f);
    __syncthreads();

    #define SCATTER_WORD(mw, toff)                                          \
        while (mw) {                                                        \
            int t = __builtin_ctz(mw); mw &= mw - 1;                        \
            atomicAdd(&acc[(t + (toff)) * BR + row], wv);                   \
        }

    // LGN synapses of this row block, flat across threads
    {
        int ls = lgn_bound[b], le = lgn_bound[b + 1];
        for (int i = ls + tid; i < le; i += 256) {
            int row  = lgn_rows[i] - r0;
            float wv = lgn_w[i];
            uint4 m  = lgn_mask[lgn_cols[i]];
            unsigned int mw;
            mw = m.x; SCATTER_WORD(mw, 0)
            mw = m.y; SCATTER_WORD(mw, 32)
            mw = m.z; SCATTER_WORD(mw, 64)
            mw = m.w; SCATTER_WORD(mw, 96)
        }
    }
    // BKG synapses
    {
        int ls = bkg_bound[b], le = bkg_bound[b + 1];
        for (int i = ls + tid; i < le; i += 256) {
            int row  = bkg_rows[i] - r0;
            float wv = bkg_w[i];
            uint4 m  = bkg_mask[bkg_cols[i]];
            unsigned int mw;
            mw = m.x; SCATTER_WORD(mw, 0)
            mw = m.y; SCATTER_WORD(mw, 32)
            mw = m.z; SCATTER_WORD(mw, 64)
            mw = m.w; SCATTER_WORD(mw, 96)
        }
    }
    #undef SCATTER_WORD
    __syncthreads();

    // epilogue: 256 threads = 2 timesteps x 128 rows per iteration
    const int hi  = tid >> 7;       // 0..1
    const int row = tid & 127;      // 0..127
    const int r   = r0 + row;
    if (r < R) {
        #pragma unroll
        for (int k = 0; k < T_STEPS / 2; ++k) {
            int t = k * 2 + hi;
            out[(size_t)t * R + r] = acc[t * BR + row];
        }
    }
}

// ---------------------------------------------------------------------------
// Fallback (small ws): inline binary search + direct float gathers.
// ---------------------------------------------------------------------------
__global__ __launch_bounds__(256) void sparse_fallback_kernel(
    const int* __restrict__ lgn_rows, const int* __restrict__ lgn_cols,
    const float* __restrict__ lgn_w, int nnz_l,
    const int* __restrict__ bkg_rows, const int* __restrict__ bkg_cols,
    const float* __restrict__ bkg_w, int nnz_b,
    const float* __restrict__ lgn_spikes, const float* __restrict__ bkg_spikes,
    int lgn_C, int bkg_C, int R,
    float* __restrict__ out)
{
    int r = blockIdx.x * 256 + threadIdx.x;
    int q = blockIdx.y;
    if (r >= R) return;

    float acc[32];
    #pragma unroll
    for (int t = 0; t < 32; ++t) acc[t] = 0.0f;

    {
        int lo = 0, hi = nnz_l;
        while (lo < hi) { int mid = (lo + hi) >> 1; if (lgn_rows[mid] < r) lo = mid + 1; else hi = mid; }
        for (int i = lo; i < nnz_l && lgn_rows[i] == r; ++i) {
            float wt = lgn_w[i];
            const float* sp = lgn_spikes + (size_t)(q * 32) * lgn_C + lgn_cols[i];
            #pragma unroll
            for (int t = 0; t < 32; ++t)
                acc[t] = fmaf(wt, sp[(size_t)t * lgn_C], acc[t]);
        }
    }
    {
        int lo = 0, hi = nnz_b;
        while (lo < hi) { int mid = (lo + hi) >> 1; if (bkg_rows[mid] < r) lo = mid + 1; else hi = mid; }
        for (int i = lo; i < nnz_b && bkg_rows[i] == r; ++i) {
            float wt = bkg_w[i];
            const float* sp = bkg_spikes + (size_t)(q * 32) * bkg_C + bkg_cols[i];
            #pragma unroll
            for (int t = 0; t < 32; ++t)
                acc[t] = fmaf(wt, sp[(size_t)t * bkg_C], acc[t]);
        }
    }

    float* op = out + (size_t)(q * 32) * R + r;
    #pragma unroll
    for (int t = 0; t < 32; ++t) op[(size_t)t * R] = acc[t];
}

extern "C" void kernel_launch(void* const* d_in, const int* in_sizes, int n_in,
                              void* d_out, int out_size, void* d_ws, size_t ws_size,
                              hipStream_t stream)
{
    const float* lgn_spikes = (const float*)d_in[0];
    const float* bkg_spikes = (const float*)d_in[1];
    const int*   lgn_rows   = (const int*)d_in[2];
    const int*   lgn_cols   = (const int*)d_in[3];
    const float* lgn_w      = (const float*)d_in[4];
    const int*   bkg_rows   = (const int*)d_in[5];
    const int*   bkg_cols   = (const int*)d_in[6];
    const float* bkg_w      = (const float*)d_in[7];
    float* out = (float*)d_out;

    const int nnz_l = in_sizes[2];
    const int nnz_b = in_sizes[5];
    const int lgn_C = in_sizes[0] / T_STEPS;   // 17400
    const int bkg_C = in_sizes[1] / T_STEPS;   // 100
    const int R     = out_size / T_STEPS;      // 200000
    const int NB    = (R + BR - 1) / BR;       // 1563 row blocks

    // ws layout (16B-aligned sections)
    size_t off = 0;
    auto take = [&](size_t bytes) { size_t o = off; off = (off + bytes + 15) & ~(size_t)15; return o; };
    size_t o_lgn_bound = take((size_t)(NB + 1) * sizeof(int));
    size_t o_bkg_bound = take((size_t)(NB + 1) * sizeof(int));
    size_t o_lgn_mask  = take((size_t)lgn_C * sizeof(uint4));
    size_t o_bkg_mask  = take((size_t)bkg_C * sizeof(uint4));
    size_t need = off;

    dim3 blk(256);

    if (ws_size >= need) {
        char* ws = (char*)d_ws;
        int* lgn_bound = (int*)(ws + o_lgn_bound);
        int* bkg_bound = (int*)(ws + o_bkg_bound);
        uint4* lgn_mask = (uint4*)(ws + o_lgn_mask);
        uint4* bkg_mask = (uint4*)(ws + o_bkg_mask);

        build_bounds_kernel<<<(NB + 1 + 255) / 256, blk, 0, stream>>>(
            lgn_rows, nnz_l, lgn_bound, bkg_rows, nnz_b, bkg_bound, NB);

        int totC = lgn_C + bkg_C;
        build_masks2_kernel<<<(totC + 255) / 256, blk, 0, stream>>>(
            lgn_spikes, lgn_C, lgn_mask, bkg_spikes, bkg_C, bkg_mask);

        sparse_scatter_kernel<<<NB, blk, 0, stream>>>(
            lgn_rows, lgn_cols, lgn_w, lgn_bound,
            bkg_rows, bkg_cols, bkg_w, bkg_bound,
            lgn_mask, bkg_mask, R, out);
    } else {
        dim3 grid_main((R + 255) / 256, 4);
        sparse_fallback_kernel<<<grid_main, blk, 0, stream>>>(
            lgn_rows, lgn_cols, lgn_w, nnz_l,
            bkg_rows, bkg_cols, bkg_w, nnz_b,
            lgn_spikes, bkg_spikes,
            lgn_C, bkg_C, R, out);
    }
}

// Round 4
// 94.414 us; speedup vs baseline: 1.0664x; 1.0664x over previous
//
#include <hip/hip_runtime.h>

#define T_STEPS 128   // timesteps (4 x 32-bit mask words)
#define BR      64    // output rows per block (LDS tile = T_STEPS*BR*4 = 32 KB)

// ---------------------------------------------------------------------------
// Kernel 1: block-granularity CSR bounds for BOTH sparse inputs.
// bound[g] = lower_bound(rows, g*BR), g in [0, nb].
// ---------------------------------------------------------------------------
__global__ __launch_bounds__(256) void build_bounds_kernel(
    const int* __restrict__ lgn_rows, int nnz_l, int* __restrict__ lgn_bound,
    const int* __restrict__ bkg_rows, int nnz_b, int* __restrict__ bkg_bound,
    int nb)
{
    int g = blockIdx.x * 256 + threadIdx.x;
    if (g > nb) return;
    int target = g * BR;
    {
        int lo = 0, hi = nnz_l;
        while (lo < hi) { int mid = (lo + hi) >> 1; if (lgn_rows[mid] < target) lo = mid + 1; else hi = mid; }
        lgn_bound[g] = lo;
    }
    {
        int lo = 0, hi = nnz_b;
        while (lo < hi) { int mid = (lo + hi) >> 1; if (bkg_rows[mid] < target) lo = mid + 1; else hi = mid; }
        bkg_bound[g] = lo;
    }
}

// ---------------------------------------------------------------------------
// Kernel 2: compress both binary spike matrices (T=128, C) into uint4 per
// column (bit t of word q = spike at t = q*32 + bit).
// ---------------------------------------------------------------------------
__global__ __launch_bounds__(256) void build_masks2_kernel(
    const float* __restrict__ lgn_spikes, int lgn_C, uint4* __restrict__ lgn_mask,
    const float* __restrict__ bkg_spikes, int bkg_C, uint4* __restrict__ bkg_mask)
{
    int c = blockIdx.x * 256 + threadIdx.x;
    const float* sp;
    uint4* mask;
    int C, cc;
    if (c < lgn_C)              { sp = lgn_spikes; mask = lgn_mask; C = lgn_C; cc = c; }
    else if (c < lgn_C + bkg_C) { sp = bkg_spikes; mask = bkg_mask; C = bkg_C; cc = c - lgn_C; }
    else return;

    unsigned int m0 = 0u, m1 = 0u, m2 = 0u, m3 = 0u;
    #pragma unroll 4
    for (int t = 0; t < 32; ++t) {
        if (sp[(size_t)(t)       * C + cc] != 0.0f) m0 |= (1u << t);
        if (sp[(size_t)(t +  32) * C + cc] != 0.0f) m1 |= (1u << t);
        if (sp[(size_t)(t +  64) * C + cc] != 0.0f) m2 |= (1u << t);
        if (sp[(size_t)(t +  96) * C + cc] != 0.0f) m3 |= (1u << t);
    }
    mask[cc] = make_uint4(m0, m1, m2, m3);
}

// ---------------------------------------------------------------------------
// Kernel 3 (main): block = 64 output rows x 128 timesteps in a 32 KB LDS
// tile acc[t][row]. 32 KB -> up to 5 blocks/CU (20 waves) for latency
// hiding. Lanes sweep the block's synapse range FLAT; one-deep software
// pipeline prefetches the next synapse's (row,w,mask) during the current
// scatter. Per synapse, only SET bits (ctz loop) trigger ds_add_f32.
// Epilogue: one coalesced write pass (out written exactly once).
// ---------------------------------------------------------------------------
__global__ __launch_bounds__(256, 5) void sparse_scatter_kernel(
    const int* __restrict__ lgn_rows, const int* __restrict__ lgn_cols,
    const float* __restrict__ lgn_w,  const int* __restrict__ lgn_bound,
    const int* __restrict__ bkg_rows, const int* __restrict__ bkg_cols,
    const float* __restrict__ bkg_w,  const int* __restrict__ bkg_bound,
    const uint4* __restrict__ lgn_mask, const uint4* __restrict__ bkg_mask,
    int R, float* __restrict__ out)
{
    __shared__ float acc[T_STEPS * BR];   // 32 KB
    const int tid = threadIdx.x;
    const int b   = blockIdx.x;
    const int r0  = b * BR;

    // zero the tile
    float4* az = (float4*)acc;
    #pragma unroll
    for (int k = 0; k < (T_STEPS * BR / 4) / 256; ++k)
        az[k * 256 + tid] = make_float4(0.f, 0.f, 0.f, 0.f);
    __syncthreads();

    #define SCATTER_WORD(mw, toff)                                          \
        while (mw) {                                                        \
            int t = __builtin_ctz(mw); mw &= mw - 1;                        \
            atomicAdd(&acc[(t + (toff)) * BR + row], wv);                   \
        }

    #define SCATTER_RANGE(rows_a, cols_a, w_a, mask_a, bnd_a)               \
    {                                                                       \
        int i1 = bnd_a[b + 1];                                              \
        int i  = bnd_a[b] + tid;                                            \
        int row = 0; float wv = 0.f;                                        \
        uint4 m = make_uint4(0u, 0u, 0u, 0u);                               \
        if (i < i1) {                                                       \
            row = rows_a[i] - r0; wv = w_a[i]; m = mask_a[cols_a[i]];       \
        }                                                                   \
        while (i < i1) {                                                    \
            int ni = i + 256;                                               \
            int nrow = 0; float nwv = 0.f;                                  \
            uint4 nm = make_uint4(0u, 0u, 0u, 0u);                          \
            if (ni < i1) {                                                  \
                nrow = rows_a[ni] - r0; nwv = w_a[ni];                      \
                nm = mask_a[cols_a[ni]];                                    \
            }                                                               \
            unsigned int mw;                                                \
            mw = m.x; SCATTER_WORD(mw, 0)                                   \
            mw = m.y; SCATTER_WORD(mw, 32)                                  \
            mw = m.z; SCATTER_WORD(mw, 64)                                  \
            mw = m.w; SCATTER_WORD(mw, 96)                                  \
            i = ni; row = nrow; wv = nwv; m = nm;                           \
        }                                                                   \
    }

    SCATTER_RANGE(lgn_rows, lgn_cols, lgn_w, lgn_mask, lgn_bound)
    SCATTER_RANGE(bkg_rows, bkg_cols, bkg_w, bkg_mask, bkg_bound)

    #undef SCATTER_RANGE
    #undef SCATTER_WORD
    __syncthreads();

    // epilogue: 256 threads = 4 timesteps x 64 rows per iteration
    const int tq  = tid >> 6;       // 0..3
    const int row = tid & 63;       // 0..63
    const int r   = r0 + row;
    if (r < R) {
        #pragma unroll
        for (int k = 0; k < T_STEPS / 4; ++k) {
            int t = k * 4 + tq;
            out[(size_t)t * R + r] = acc[t * BR + row];
        }
    }
}

// ---------------------------------------------------------------------------
// Fallback (small ws): inline binary search + direct float gathers.
// ---------------------------------------------------------------------------
__global__ __launch_bounds__(256) void sparse_fallback_kernel(
    const int* __restrict__ lgn_rows, const int* __restrict__ lgn_cols,
    const float* __restrict__ lgn_w, int nnz_l,
    const int* __restrict__ bkg_rows, const int* __restrict__ bkg_cols,
    const float* __restrict__ bkg_w, int nnz_b,
    const float* __restrict__ lgn_spikes, const float* __restrict__ bkg_spikes,
    int lgn_C, int bkg_C, int R,
    float* __restrict__ out)
{
    int r = blockIdx.x * 256 + threadIdx.x;
    int q = blockIdx.y;
    if (r >= R) return;

    float acc[32];
    #pragma unroll
    for (int t = 0; t < 32; ++t) acc[t] = 0.0f;

    {
        int lo = 0, hi = nnz_l;
        while (lo < hi) { int mid = (lo + hi) >> 1; if (lgn_rows[mid] < r) lo = mid + 1; else hi = mid; }
        for (int i = lo; i < nnz_l && lgn_rows[i] == r; ++i) {
            float wt = lgn_w[i];
            const float* sp = lgn_spikes + (size_t)(q * 32) * lgn_C + lgn_cols[i];
            #pragma unroll
            for (int t = 0; t < 32; ++t)
                acc[t] = fmaf(wt, sp[(size_t)t * lgn_C], acc[t]);
        }
    }
    {
        int lo = 0, hi = nnz_b;
        while (lo < hi) { int mid = (lo + hi) >> 1; if (bkg_rows[mid] < r) lo = mid + 1; else hi = mid; }
        for (int i = lo; i < nnz_b && bkg_rows[i] == r; ++i) {
            float wt = bkg_w[i];
            const float* sp = bkg_spikes + (size_t)(q * 32) * bkg_C + bkg_cols[i];
            #pragma unroll
            for (int t = 0; t < 32; ++t)
                acc[t] = fmaf(wt, sp[(size_t)t * bkg_C], acc[t]);
        }
    }

    float* op = out + (size_t)(q * 32) * R + r;
    #pragma unroll
    for (int t = 0; t < 32; ++t) op[(size_t)t * R] = acc[t];
}

extern "C" void kernel_launch(void* const* d_in, const int* in_sizes, int n_in,
                              void* d_out, int out_size, void* d_ws, size_t ws_size,
                              hipStream_t stream)
{
    const float* lgn_spikes = (const float*)d_in[0];
    const float* bkg_spikes = (const float*)d_in[1];
    const int*   lgn_rows   = (const int*)d_in[2];
    const int*   lgn_cols   = (const int*)d_in[3];
    const float* lgn_w      = (const float*)d_in[4];
    const int*   bkg_rows   = (const int*)d_in[5];
    const int*   bkg_cols   = (const int*)d_in[6];
    const float* bkg_w      = (const float*)d_in[7];
    float* out = (float*)d_out;

    const int nnz_l = in_sizes[2];
    const int nnz_b = in_sizes[5];
    const int lgn_C = in_sizes[0] / T_STEPS;   // 17400
    const int bkg_C = in_sizes[1] / T_STEPS;   // 100
    const int R     = out_size / T_STEPS;      // 200000
    const int NB    = (R + BR - 1) / BR;       // 3125 row blocks

    // ws layout (16B-aligned sections)
    size_t off = 0;
    auto take = [&](size_t bytes) { size_t o = off; off = (off + bytes + 15) & ~(size_t)15; return o; };
    size_t o_lgn_bound = take((size_t)(NB + 1) * sizeof(int));
    size_t o_bkg_bound = take((size_t)(NB + 1) * sizeof(int));
    size_t o_lgn_mask  = take((size_t)lgn_C * sizeof(uint4));
    size_t o_bkg_mask  = take((size_t)bkg_C * sizeof(uint4));
    size_t need = off;

    dim3 blk(256);

    if (ws_size >= need) {
        char* ws = (char*)d_ws;
        int* lgn_bound = (int*)(ws + o_lgn_bound);
        int* bkg_bound = (int*)(ws + o_bkg_bound);
        uint4* lgn_mask = (uint4*)(ws + o_lgn_mask);
        uint4* bkg_mask = (uint4*)(ws + o_bkg_mask);

        build_bounds_kernel<<<(NB + 1 + 255) / 256, blk, 0, stream>>>(
            lgn_rows, nnz_l, lgn_bound, bkg_rows, nnz_b, bkg_bound, NB);

        int totC = lgn_C + bkg_C;
        build_masks2_kernel<<<(totC + 255) / 256, blk, 0, stream>>>(
            lgn_spikes, lgn_C, lgn_mask, bkg_spikes, bkg_C, bkg_mask);

        sparse_scatter_kernel<<<NB, blk, 0, stream>>>(
            lgn_rows, lgn_cols, lgn_w, lgn_bound,
            bkg_rows, bkg_cols, bkg_w, bkg_bound,
            lgn_mask, bkg_mask, R, out);
    } else {
        dim3 grid_main((R + 255) / 256, 4);
        sparse_fallback_kernel<<<grid_main, blk, 0, stream>>>(
            lgn_rows, lgn_cols, lgn_w, nnz_l,
            bkg_rows, bkg_cols, bkg_w, nnz_b,
            lgn_spikes, bkg_spikes,
            lgn_C, bkg_C, R, out);
    }
}